// Round 1
// baseline (1360.022 us; speedup 1.0000x reference)
//
#include <hip/hip_runtime.h>
#include <hip/hip_bf16.h>

typedef _Float16 h16;
typedef _Float16 f16x8 __attribute__((ext_vector_type(8)));
typedef float f32x4 __attribute__((ext_vector_type(4)));

constexpr int T = 8192, H = 1024, F = 2816, E = 8;
constexpr int NENT = T * 2;     // 16384 (token, expert) entries total
constexpr int SLACK = 128;
constexpr int MT = T / 128;     // 64 max M-tiles per expert
constexpr int NT1 = F / 128;    // 22
constexpr int NT2 = H / 128;    // 8

// ---------------- routing: top-2 of 8, renormalized softmax weights ----------------
__global__ void k_routing(const float* __restrict__ logits,
                          int* __restrict__ top_i, float* __restrict__ top_w,
                          int* __restrict__ counts) {
  int t = blockIdx.x * blockDim.x + threadIdx.x;
  if (t >= T) return;
  float l[E];
#pragma unroll
  for (int j = 0; j < E; ++j) l[j] = logits[t * E + j];
  int i1 = 0; float v1 = l[0];
#pragma unroll
  for (int j = 1; j < E; ++j) if (l[j] > v1) { v1 = l[j]; i1 = j; }
  int i2 = -1; float v2 = -3.4e38f;
#pragma unroll
  for (int j = 0; j < E; ++j) if (j != i1 && l[j] > v2) { v2 = l[j]; i2 = j; }
  // renormalized top-2 softmax == softmax over the two logits
  float e2 = __expf(v2 - v1);
  float inv = 1.0f / (1.0f + e2);
  top_i[2 * t] = i1; top_i[2 * t + 1] = i2;
  top_w[2 * t] = inv; top_w[2 * t + 1] = e2 * inv;
  atomicAdd(&counts[i1], 1);
  atomicAdd(&counts[i2], 1);
}

__global__ void k_init_counts(int* counts) {
  if (threadIdx.x < E) counts[threadIdx.x] = 0;
}

__global__ void k_prefix(const int* __restrict__ counts, int* __restrict__ offs,
                         int* __restrict__ fill) {
  if (threadIdx.x == 0) {
    int s = 0;
    for (int e = 0; e < E; ++e) { offs[e] = s; s += counts[e]; fill[e] = 0; }
  }
}

__global__ void k_scatter(const int* __restrict__ top_i, const float* __restrict__ top_w,
                          const int* __restrict__ offs, int* __restrict__ fill,
                          int* __restrict__ etok, float* __restrict__ ew) {
  int t = blockIdx.x * blockDim.x + threadIdx.x;
  if (t >= T) return;
#pragma unroll
  for (int k = 0; k < 2; ++k) {
    int e = top_i[2 * t + k];
    int pos = atomicAdd(&fill[e], 1);
    int idx = offs[e] + pos;
    etok[idx] = t;
    ew[idx] = top_w[2 * t + k];
  }
}

// ---------------- x fp32 -> fp16 ----------------
__global__ void k_cvt_x(const float* __restrict__ x, h16* __restrict__ x16) {
  size_t i = (size_t)(blockIdx.x * blockDim.x + threadIdx.x) * 8;
  float4 a = *(const float4*)(x + i);
  float4 b = *(const float4*)(x + i + 4);
  f16x8 h = {(h16)a.x, (h16)a.y, (h16)a.z, (h16)a.w,
             (h16)b.x, (h16)b.y, (h16)b.z, (h16)b.w};
  *(f16x8*)(x16 + i) = h;
}

__global__ void k_zero_out(float* __restrict__ p) {
  int i = blockIdx.x * blockDim.x + threadIdx.x;
  ((float4*)p)[i] = make_float4(0.f, 0.f, 0.f, 0.f);
}

// ---------------- GEMM1: act = silu(Xg @ w1^T) * (Xg @ w3^T), fp16 out ----------------
__launch_bounds__(256, 2)
__global__ void k_gemm1(const h16* __restrict__ x16,
                        const float* __restrict__ w1, const float* __restrict__ w3,
                        const int* __restrict__ counts, const int* __restrict__ offs,
                        const int* __restrict__ etok, h16* __restrict__ act) {
  int bid = blockIdx.x;
  int e  = bid / (MT * NT1);
  int r  = bid % (MT * NT1);
  int nt = r / MT;
  int mt = r % MT;
  int n_e = counts[e];
  if (mt * 128 >= n_e) return;
  int base = offs[e];

  __shared__ h16 As[128][40];
  __shared__ h16 B1s[128][40];
  __shared__ h16 B3s[128][40];

  int tid = threadIdx.x;
  int srow = tid >> 1;
  int scol = (tid & 1) * 16;

  int er = mt * 128 + srow; if (er > n_e - 1) er = n_e - 1;
  const h16*  xrow  = x16 + (size_t)etok[base + er] * H;
  const float* w1row = w1 + ((size_t)e * F + (size_t)nt * 128 + srow) * H;
  const float* w3row = w3 + ((size_t)e * F + (size_t)nt * 128 + srow) * H;

  int lane = tid & 63;
  int wid  = tid >> 6;
  int wm = (wid >> 1) * 64, wn = (wid & 1) * 64;
  int lr = lane & 15;
  int lk = (lane >> 4) * 8;

  f32x4 accg[4][4] = {{{0.f,0.f,0.f,0.f}}};
  f32x4 accu[4][4] = {{{0.f,0.f,0.f,0.f}}};

  for (int k0 = 0; k0 < H; k0 += 32) {
    // stage A (fp16 direct)
    *(f16x8*)&As[srow][scol]     = *(const f16x8*)(xrow + k0 + scol);
    *(f16x8*)&As[srow][scol + 8] = *(const f16x8*)(xrow + k0 + scol + 8);
    // stage B1/B3 (fp32 -> fp16)
    {
      const float* p = w1row + k0 + scol;
      float4 f0 = *(const float4*)(p);
      float4 f1 = *(const float4*)(p + 4);
      float4 f2 = *(const float4*)(p + 8);
      float4 f3 = *(const float4*)(p + 12);
      f16x8 h0 = {(h16)f0.x,(h16)f0.y,(h16)f0.z,(h16)f0.w,(h16)f1.x,(h16)f1.y,(h16)f1.z,(h16)f1.w};
      f16x8 h1 = {(h16)f2.x,(h16)f2.y,(h16)f2.z,(h16)f2.w,(h16)f3.x,(h16)f3.y,(h16)f3.z,(h16)f3.w};
      *(f16x8*)&B1s[srow][scol]     = h0;
      *(f16x8*)&B1s[srow][scol + 8] = h1;
    }
    {
      const float* p = w3row + k0 + scol;
      float4 f0 = *(const float4*)(p);
      float4 f1 = *(const float4*)(p + 4);
      float4 f2 = *(const float4*)(p + 8);
      float4 f3 = *(const float4*)(p + 12);
      f16x8 h0 = {(h16)f0.x,(h16)f0.y,(h16)f0.z,(h16)f0.w,(h16)f1.x,(h16)f1.y,(h16)f1.z,(h16)f1.w};
      f16x8 h1 = {(h16)f2.x,(h16)f2.y,(h16)f2.z,(h16)f2.w,(h16)f3.x,(h16)f3.y,(h16)f3.z,(h16)f3.w};
      *(f16x8*)&B3s[srow][scol]     = h0;
      *(f16x8*)&B3s[srow][scol + 8] = h1;
    }
    __syncthreads();

    f16x8 av[4], b1v[4], b3v[4];
#pragma unroll
    for (int mi = 0; mi < 4; ++mi) av[mi] = *(const f16x8*)&As[wm + mi * 16 + lr][lk];
#pragma unroll
    for (int ni = 0; ni < 4; ++ni) {
      b1v[ni] = *(const f16x8*)&B1s[wn + ni * 16 + lr][lk];
      b3v[ni] = *(const f16x8*)&B3s[wn + ni * 16 + lr][lk];
    }
#pragma unroll
    for (int mi = 0; mi < 4; ++mi)
#pragma unroll
      for (int ni = 0; ni < 4; ++ni) {
        accg[mi][ni] = __builtin_amdgcn_mfma_f32_16x16x32_f16(av[mi], b1v[ni], accg[mi][ni], 0, 0, 0);
        accu[mi][ni] = __builtin_amdgcn_mfma_f32_16x16x32_f16(av[mi], b3v[ni], accu[mi][ni], 0, 0, 0);
      }
    __syncthreads();
  }

  // epilogue: silu(g)*u -> fp16 act, masked to valid rows
#pragma unroll
  for (int mi = 0; mi < 4; ++mi) {
#pragma unroll
    for (int rr = 0; rr < 4; ++rr) {
      int grow = mt * 128 + wm + mi * 16 + (lane >> 4) * 4 + rr;
      if (grow < n_e) {
        size_t rowb = (size_t)(base + grow) * F + (size_t)nt * 128 + wn;
#pragma unroll
        for (int ni = 0; ni < 4; ++ni) {
          float g = accg[mi][ni][rr];
          float u = accu[mi][ni][rr];
          float s = g / (1.0f + __expf(-g)) * u;
          act[rowb + ni * 16 + lr] = (h16)s;
        }
      }
    }
  }
}

// ---------------- GEMM2: out += coeff * (act @ w2^T) ----------------
__launch_bounds__(256, 2)
__global__ void k_gemm2(const h16* __restrict__ act, const float* __restrict__ w2,
                        const int* __restrict__ counts, const int* __restrict__ offs,
                        const int* __restrict__ etok, const float* __restrict__ ew,
                        float* __restrict__ out) {
  int bid = blockIdx.x;
  int e  = bid / (MT * NT2);
  int r  = bid % (MT * NT2);
  int nt = r / MT;
  int mt = r % MT;
  int n_e = counts[e];
  if (mt * 128 >= n_e) return;
  int base = offs[e];

  __shared__ h16 As[128][40];
  __shared__ h16 Bs[128][40];

  int tid = threadIdx.x;
  int srow = tid >> 1;
  int scol = (tid & 1) * 16;

  const h16*  arow  = act + (size_t)(base + mt * 128 + srow) * F;
  const float* w2row = w2 + ((size_t)e * H + (size_t)nt * 128 + srow) * F;

  int lane = tid & 63;
  int wid  = tid >> 6;
  int wm = (wid >> 1) * 64, wn = (wid & 1) * 64;
  int lr = lane & 15;
  int lk = (lane >> 4) * 8;

  f32x4 acc[4][4] = {{{0.f,0.f,0.f,0.f}}};

  for (int k0 = 0; k0 < F; k0 += 32) {
    *(f16x8*)&As[srow][scol]     = *(const f16x8*)(arow + k0 + scol);
    *(f16x8*)&As[srow][scol + 8] = *(const f16x8*)(arow + k0 + scol + 8);
    {
      const float* p = w2row + k0 + scol;
      float4 f0 = *(const float4*)(p);
      float4 f1 = *(const float4*)(p + 4);
      float4 f2 = *(const float4*)(p + 8);
      float4 f3 = *(const float4*)(p + 12);
      f16x8 h0 = {(h16)f0.x,(h16)f0.y,(h16)f0.z,(h16)f0.w,(h16)f1.x,(h16)f1.y,(h16)f1.z,(h16)f1.w};
      f16x8 h1 = {(h16)f2.x,(h16)f2.y,(h16)f2.z,(h16)f2.w,(h16)f3.x,(h16)f3.y,(h16)f3.z,(h16)f3.w};
      *(f16x8*)&Bs[srow][scol]     = h0;
      *(f16x8*)&Bs[srow][scol + 8] = h1;
    }
    __syncthreads();

    f16x8 av[4], bv[4];
#pragma unroll
    for (int mi = 0; mi < 4; ++mi) av[mi] = *(const f16x8*)&As[wm + mi * 16 + lr][lk];
#pragma unroll
    for (int ni = 0; ni < 4; ++ni) bv[ni] = *(const f16x8*)&Bs[wn + ni * 16 + lr][lk];
#pragma unroll
    for (int mi = 0; mi < 4; ++mi)
#pragma unroll
      for (int ni = 0; ni < 4; ++ni)
        acc[mi][ni] = __builtin_amdgcn_mfma_f32_16x16x32_f16(av[mi], bv[ni], acc[mi][ni], 0, 0, 0);
    __syncthreads();
  }

#pragma unroll
  for (int mi = 0; mi < 4; ++mi) {
#pragma unroll
    for (int rr = 0; rr < 4; ++rr) {
      int grow = mt * 128 + wm + mi * 16 + (lane >> 4) * 4 + rr;
      if (grow < n_e) {
        int tok = etok[base + grow];
        float w = ew[base + grow];
        float* orow = out + (size_t)tok * H + (size_t)nt * 128 + wn;
#pragma unroll
        for (int ni = 0; ni < 4; ++ni)
          atomicAdd(orow + ni * 16 + lr, w * acc[mi][ni][rr]);
      }
    }
  }
}

extern "C" void kernel_launch(void* const* d_in, const int* in_sizes, int n_in,
                              void* d_out, int out_size, void* d_ws, size_t ws_size,
                              hipStream_t stream) {
  const float* x  = (const float*)d_in[0];
  const float* rl = (const float*)d_in[1];
  const float* w1 = (const float*)d_in[2];
  const float* w3 = (const float*)d_in[3];
  const float* w2 = (const float*)d_in[4];
  float* out = (float*)d_out;

  char* ws = (char*)d_ws;
  size_t off = 0;
  auto alloc = [&](size_t bytes) -> void* {
    void* p = ws + off;
    off = (off + bytes + 255) & ~(size_t)255;
    return p;
  };
  h16*   x16  = (h16*)  alloc((size_t)T * H * sizeof(h16));
  h16*   act  = (h16*)  alloc((size_t)(NENT + SLACK) * F * sizeof(h16));
  int*   etok = (int*)  alloc((size_t)(NENT + SLACK) * sizeof(int));
  float* ew   = (float*)alloc((size_t)(NENT + SLACK) * sizeof(float));
  int*   topi = (int*)  alloc((size_t)NENT * sizeof(int));
  float* topw = (float*)alloc((size_t)NENT * sizeof(float));
  int* counts = (int*)  alloc(64);
  int* offs   = (int*)  alloc(64);
  int* fill   = (int*)  alloc(64);
  (void)ws_size; (void)in_sizes; (void)n_in;

  k_init_counts<<<1, 64, 0, stream>>>(counts);
  k_zero_out<<<out_size / (256 * 4), 256, 0, stream>>>(out);
  k_routing<<<(T + 255) / 256, 256, 0, stream>>>(rl, topi, topw, counts);
  k_prefix<<<1, 64, 0, stream>>>(counts, offs, fill);
  k_scatter<<<(T + 255) / 256, 256, 0, stream>>>(topi, topw, offs, fill, etok, ew);
  k_cvt_x<<<(T * H / 8) / 256, 256, 0, stream>>>(x, x16);
  k_gemm1<<<E * MT * NT1, 256, 0, stream>>>(x16, w1, w3, counts, offs, etok, act);
  k_gemm2<<<E * MT * NT2, 256, 0, stream>>>(act, w2, counts, offs, etok, ew, out);
}

// Round 2
// 894.305 us; speedup vs baseline: 1.5208x; 1.5208x over previous
//
#include <hip/hip_runtime.h>
#include <hip/hip_bf16.h>

typedef _Float16 h16;
typedef _Float16 f16x8 __attribute__((ext_vector_type(8)));
typedef float f32x4 __attribute__((ext_vector_type(4)));

constexpr int T = 8192, H = 1024, F = 2816, E = 8;
constexpr int NENT = T * 2;
constexpr int SLACK = 128;
constexpr int MT = T / 128;     // 64 max M-tiles per expert
constexpr int NT1 = F / 128;    // 22
constexpr int NT2 = H / 128;    // 8

#define GLD16(gptr, lptr)                                                        \
  __builtin_amdgcn_global_load_lds(                                              \
      (const __attribute__((address_space(1))) unsigned int*)(gptr),             \
      (__attribute__((address_space(3))) unsigned int*)(lptr), 16, 0, 0)

// Swizzled LDS tile: 128 rows x 32 h16 (8 KB). Logical (row, kslot s in [0,4))
// -> physical byte. Superrow r2=row>>1 is 128 B; slot8 = (row&1)*4 + s, XOR'd
// with r2&7. Read-side: 16 lanes reading 16 consecutive rows at one slot land
// 2-way per bank quad (free, m136).
__device__ __forceinline__ int lds_off(int row, int s) {
  int r2 = row >> 1;
  int p = (((row & 1) << 2) | s) ^ (r2 & 7);
  return r2 * 128 + p * 16;
}
// Write-side inverse for global_load_lds (linear dest): chunk c (1 KB), lane i
// writes LDS byte c*1024 + i*16 = superrow r2=c*8+(i>>3), physical slot p=i&7.
// The data that belongs there is logical row/col:
__device__ __forceinline__ void inv_rowcol(int c, int i, int& row, int& col) {
  int r2 = c * 8 + (i >> 3);
  int slot8 = (i & 7) ^ (r2 & 7);
  row = r2 * 2 + (slot8 >> 2);
  col = (slot8 & 3) * 8;
}

// ---------------- routing ----------------
__global__ void k_routing(const float* __restrict__ logits,
                          int* __restrict__ top_i, float* __restrict__ top_w,
                          int* __restrict__ counts) {
  int t = blockIdx.x * blockDim.x + threadIdx.x;
  if (t >= T) return;
  float l[E];
#pragma unroll
  for (int j = 0; j < E; ++j) l[j] = logits[t * E + j];
  int i1 = 0; float v1 = l[0];
#pragma unroll
  for (int j = 1; j < E; ++j) if (l[j] > v1) { v1 = l[j]; i1 = j; }
  int i2 = -1; float v2 = -3.4e38f;
#pragma unroll
  for (int j = 0; j < E; ++j) if (j != i1 && l[j] > v2) { v2 = l[j]; i2 = j; }
  float e2 = __expf(v2 - v1);
  float inv = 1.0f / (1.0f + e2);
  top_i[2 * t] = i1; top_i[2 * t + 1] = i2;
  top_w[2 * t] = inv; top_w[2 * t + 1] = e2 * inv;
  atomicAdd(&counts[i1], 1);
  atomicAdd(&counts[i2], 1);
}

__global__ void k_init_counts(int* counts) {
  if (threadIdx.x < E) counts[threadIdx.x] = 0;
}

__global__ void k_prefix(const int* __restrict__ counts, int* __restrict__ offs,
                         int* __restrict__ fill) {
  if (threadIdx.x == 0) {
    int s = 0;
    for (int e = 0; e < E; ++e) { offs[e] = s; s += counts[e]; fill[e] = 0; }
  }
}

__global__ void k_scatter(const int* __restrict__ top_i, const float* __restrict__ top_w,
                          const int* __restrict__ offs, int* __restrict__ fill,
                          int* __restrict__ etok, float* __restrict__ ew) {
  int t = blockIdx.x * blockDim.x + threadIdx.x;
  if (t >= T) return;
#pragma unroll
  for (int k = 0; k < 2; ++k) {
    int e = top_i[2 * t + k];
    int pos = atomicAdd(&fill[e], 1);
    int idx = offs[e] + pos;
    etok[idx] = t;
    ew[idx] = top_w[2 * t + k];
  }
}

// ---------------- fp32 -> fp16 converters ----------------
__global__ void k_cvt(const float* __restrict__ s, h16* __restrict__ d) {
  size_t i = (size_t)(blockIdx.x * blockDim.x + threadIdx.x) * 8;
  float4 a = *(const float4*)(s + i);
  float4 b = *(const float4*)(s + i + 4);
  f16x8 h = {(h16)a.x, (h16)a.y, (h16)a.z, (h16)a.w,
             (h16)b.x, (h16)b.y, (h16)b.z, (h16)b.w};
  *(f16x8*)(d + i) = h;
}

__global__ void k_zero_out(float* __restrict__ p) {
  int i = blockIdx.x * blockDim.x + threadIdx.x;
  ((float4*)p)[i] = make_float4(0.f, 0.f, 0.f, 0.f);
}

// ---------------- GEMM1: act = silu(Xg @ w1^T) * (Xg @ w3^T) ----------------
template <bool BPRE>
__launch_bounds__(256, 2)
__global__ void k_gemm1(const h16* __restrict__ x16,
                        const h16* __restrict__ w1h, const h16* __restrict__ w3h,
                        const float* __restrict__ w1f, const float* __restrict__ w3f,
                        const int* __restrict__ counts, const int* __restrict__ offs,
                        const int* __restrict__ etok, h16* __restrict__ act) {
  int bid = blockIdx.x;
  int e  = bid / (MT * NT1);
  int r  = bid % (MT * NT1);
  int nt = r / MT;
  int mt = r % MT;
  int n_e = counts[e];
  if (mt * 128 >= n_e) return;
  int base = offs[e];

  __shared__ h16 As[128 * 32];
  __shared__ h16 B1s[128 * 32];
  __shared__ h16 B3s[128 * 32];

  int tid = threadIdx.x;
  int lane = tid & 63, wid = tid >> 6;
  int wm = (wid >> 1) * 64, wn = (wid & 1) * 64;
  int lr = lane & 15;
  int ls = lane >> 4;   // k-slot

  // staging source pointers (lane-static): chunks c = wid*2 + j
  const h16* ga[2]; const h16* gb1[2]; const h16* gb3[2];
  const float* fb1a; const float* fb3a; int fldso; // !BPRE reg-staging (per thread, 2 slots)
  int frow_s = 0, fcol_s = 0;
#pragma unroll
  for (int j = 0; j < 2; ++j) {
    int c = wid * 2 + j;
    int row, col;
    inv_rowcol(c, lane, row, col);
    int gr = mt * 128 + row; if (gr >= n_e) gr = n_e - 1;
    ga[j] = x16 + (size_t)etok[base + gr] * H + col;
    if (BPRE) {
      size_t wrow = ((size_t)e * F + (size_t)nt * 128 + row) * H + col;
      gb1[j] = w1h + wrow;
      gb3[j] = w3h + wrow;
    }
  }
  if (!BPRE) {
    // thread-level: 512 slot-writes per matrix, 2 per thread (handled as one
    // 32B fp32 read -> 16B fp16 write each); use slot indices tid*2, tid*2+1
    int idx = tid * 2;
    int r2 = idx >> 3, p = idx & 7;
    int slot8 = p ^ (r2 & 7);
    frow_s = r2 * 2 + (slot8 >> 2);
    fcol_s = (slot8 & 3) * 8;
    fldso = r2 * 128 + p * 16;
    size_t wrow = ((size_t)e * F + (size_t)nt * 128 + frow_s) * H + fcol_s;
    fb1a = w1f + wrow;
    fb3a = w3f + wrow;
  }

  f32x4 accg[4][4] = {{{0.f,0.f,0.f,0.f}}};
  f32x4 accu[4][4] = {{{0.f,0.f,0.f,0.f}}};

  // hoisted frag LDS offsets
  int aoff[4], boff[4];
#pragma unroll
  for (int i = 0; i < 4; ++i) {
    aoff[i] = lds_off(wm + i * 16 + lr, ls);
    boff[i] = lds_off(wn + i * 16 + lr, ls);
  }

  for (int k0 = 0; k0 < H; k0 += 32) {
#pragma unroll
    for (int j = 0; j < 2; ++j) {
      int c = wid * 2 + j;
      GLD16(ga[j] + k0, (char*)As + c * 1024);
      if (BPRE) {
        GLD16(gb1[j] + k0, (char*)B1s + c * 1024);
        GLD16(gb3[j] + k0, (char*)B3s + c * 1024);
      }
    }
    if (!BPRE) {
#pragma unroll
      for (int j = 0; j < 2; ++j) {
        const float* p1 = fb1a + (size_t)j * H + k0;  // second slot is next row? no:
        // second slot idx = tid*2+1 -> same r2, p+1 when tid*2 even.. recompute:
        int idx = tid * 2 + j;
        int r2 = idx >> 3, pp = idx & 7;
        int slot8 = pp ^ (r2 & 7);
        int row = r2 * 2 + (slot8 >> 2);
        int col = (slot8 & 3) * 8;
        size_t wrow = ((size_t)e * F + (size_t)nt * 128 + row) * H + col + k0;
        int ldso = r2 * 128 + pp * 16;
        float4 f0 = *(const float4*)(w1f + wrow);
        float4 f1 = *(const float4*)(w1f + wrow + 4);
        f16x8 h0 = {(h16)f0.x,(h16)f0.y,(h16)f0.z,(h16)f0.w,(h16)f1.x,(h16)f1.y,(h16)f1.z,(h16)f1.w};
        *(f16x8*)((char*)B1s + ldso) = h0;
        float4 g0 = *(const float4*)(w3f + wrow);
        float4 g1 = *(const float4*)(w3f + wrow + 4);
        f16x8 h1 = {(h16)g0.x,(h16)g0.y,(h16)g0.z,(h16)g0.w,(h16)g1.x,(h16)g1.y,(h16)g1.z,(h16)g1.w};
        *(f16x8*)((char*)B3s + ldso) = h1;
      }
    }
    __syncthreads();

    f16x8 av[4], b1v[4], b3v[4];
#pragma unroll
    for (int mi = 0; mi < 4; ++mi) av[mi] = *(const f16x8*)((const char*)As + aoff[mi]);
#pragma unroll
    for (int ni = 0; ni < 4; ++ni) {
      b1v[ni] = *(const f16x8*)((const char*)B1s + boff[ni]);
      b3v[ni] = *(const f16x8*)((const char*)B3s + boff[ni]);
    }
#pragma unroll
    for (int mi = 0; mi < 4; ++mi)
#pragma unroll
      for (int ni = 0; ni < 4; ++ni) {
        accg[mi][ni] = __builtin_amdgcn_mfma_f32_16x16x32_f16(av[mi], b1v[ni], accg[mi][ni], 0, 0, 0);
        accu[mi][ni] = __builtin_amdgcn_mfma_f32_16x16x32_f16(av[mi], b3v[ni], accu[mi][ni], 0, 0, 0);
      }
    __syncthreads();
  }

#pragma unroll
  for (int mi = 0; mi < 4; ++mi) {
#pragma unroll
    for (int rr = 0; rr < 4; ++rr) {
      int grow = mt * 128 + wm + mi * 16 + (lane >> 4) * 4 + rr;
      if (grow < n_e) {
        size_t rowb = (size_t)(base + grow) * F + (size_t)nt * 128 + wn;
#pragma unroll
        for (int ni = 0; ni < 4; ++ni) {
          float g = accg[mi][ni][rr];
          float u = accu[mi][ni][rr];
          float s = g / (1.0f + __expf(-g)) * u;
          act[rowb + ni * 16 + lr] = (h16)s;
        }
      }
    }
  }
}

// ---------------- GEMM2: out += coeff * (act @ w2^T) ----------------
template <bool BPRE>
__launch_bounds__(256, 2)
__global__ void k_gemm2(const h16* __restrict__ act,
                        const h16* __restrict__ w2h, const float* __restrict__ w2f,
                        const int* __restrict__ counts, const int* __restrict__ offs,
                        const int* __restrict__ etok, const float* __restrict__ ew,
                        float* __restrict__ out) {
  int bid = blockIdx.x;
  int e  = bid / (MT * NT2);
  int r  = bid % (MT * NT2);
  int nt = r / MT;
  int mt = r % MT;
  int n_e = counts[e];
  if (mt * 128 >= n_e) return;
  int base = offs[e];

  __shared__ h16 As[128 * 32];
  __shared__ h16 Bs[128 * 32];

  int tid = threadIdx.x;
  int lane = tid & 63, wid = tid >> 6;
  int wm = (wid >> 1) * 64, wn = (wid & 1) * 64;
  int lr = lane & 15;
  int ls = lane >> 4;

  const h16* ga[2]; const h16* gb[2];
#pragma unroll
  for (int j = 0; j < 2; ++j) {
    int c = wid * 2 + j;
    int row, col;
    inv_rowcol(c, lane, row, col);
    int gr = mt * 128 + row; if (gr >= n_e) gr = n_e - 1;
    ga[j] = act + (size_t)(base + gr) * F + col;
    if (BPRE) gb[j] = w2h + ((size_t)e * H + (size_t)nt * 128 + row) * F + col;
  }

  f32x4 acc[4][4] = {{{0.f,0.f,0.f,0.f}}};

  int aoff[4], boff[4];
#pragma unroll
  for (int i = 0; i < 4; ++i) {
    aoff[i] = lds_off(wm + i * 16 + lr, ls);
    boff[i] = lds_off(wn + i * 16 + lr, ls);
  }

  for (int k0 = 0; k0 < F; k0 += 32) {
#pragma unroll
    for (int j = 0; j < 2; ++j) {
      int c = wid * 2 + j;
      GLD16(ga[j] + k0, (char*)As + c * 1024);
      if (BPRE) GLD16(gb[j] + k0, (char*)Bs + c * 1024);
    }
    if (!BPRE) {
#pragma unroll
      for (int j = 0; j < 2; ++j) {
        int idx = tid * 2 + j;
        int r2 = idx >> 3, pp = idx & 7;
        int slot8 = pp ^ (r2 & 7);
        int row = r2 * 2 + (slot8 >> 2);
        int col = (slot8 & 3) * 8;
        size_t wrow = ((size_t)e * H + (size_t)nt * 128 + row) * F + col + k0;
        int ldso = r2 * 128 + pp * 16;
        float4 f0 = *(const float4*)(w2f + wrow);
        float4 f1 = *(const float4*)(w2f + wrow + 4);
        f16x8 h0 = {(h16)f0.x,(h16)f0.y,(h16)f0.z,(h16)f0.w,(h16)f1.x,(h16)f1.y,(h16)f1.z,(h16)f1.w};
        *(f16x8*)((char*)Bs + ldso) = h0;
      }
    }
    __syncthreads();

    f16x8 av[4], bv[4];
#pragma unroll
    for (int mi = 0; mi < 4; ++mi) av[mi] = *(const f16x8*)((const char*)As + aoff[mi]);
#pragma unroll
    for (int ni = 0; ni < 4; ++ni) bv[ni] = *(const f16x8*)((const char*)Bs + boff[ni]);
#pragma unroll
    for (int mi = 0; mi < 4; ++mi)
#pragma unroll
      for (int ni = 0; ni < 4; ++ni)
        acc[mi][ni] = __builtin_amdgcn_mfma_f32_16x16x32_f16(av[mi], bv[ni], acc[mi][ni], 0, 0, 0);
    __syncthreads();
  }

#pragma unroll
  for (int mi = 0; mi < 4; ++mi) {
#pragma unroll
    for (int rr = 0; rr < 4; ++rr) {
      int grow = mt * 128 + wm + mi * 16 + (lane >> 4) * 4 + rr;
      if (grow < n_e) {
        int tok = etok[base + grow];
        float w = ew[base + grow];
        float* orow = out + (size_t)tok * H + (size_t)nt * 128 + wn;
#pragma unroll
        for (int ni = 0; ni < 4; ++ni)
          atomicAdd(orow + ni * 16 + lr, w * acc[mi][ni][rr]);
      }
    }
  }
}

extern "C" void kernel_launch(void* const* d_in, const int* in_sizes, int n_in,
                              void* d_out, int out_size, void* d_ws, size_t ws_size,
                              hipStream_t stream) {
  const float* x  = (const float*)d_in[0];
  const float* rl = (const float*)d_in[1];
  const float* w1 = (const float*)d_in[2];
  const float* w3 = (const float*)d_in[3];
  const float* w2 = (const float*)d_in[4];
  float* out = (float*)d_out;

  char* ws = (char*)d_ws;
  size_t off = 0;
  auto alloc = [&](size_t bytes) -> void* {
    void* p = ws + off;
    off = (off + bytes + 255) & ~(size_t)255;
    return p;
  };
  h16*   x16  = (h16*)  alloc((size_t)T * H * sizeof(h16));
  h16*   act  = (h16*)  alloc((size_t)(NENT + SLACK) * F * sizeof(h16));
  int*   etok = (int*)  alloc((size_t)(NENT + SLACK) * sizeof(int));
  float* ew   = (float*)alloc((size_t)(NENT + SLACK) * sizeof(float));
  int*   topi = (int*)  alloc((size_t)NENT * sizeof(int));
  float* topw = (float*)alloc((size_t)NENT * sizeof(float));
  int* counts = (int*)  alloc(64);
  int* offs   = (int*)  alloc(64);
  int* fill   = (int*)  alloc(64);
  // weights last so the fallback layout is a prefix
  h16* w1h = (h16*)alloc((size_t)E * F * H * sizeof(h16));
  h16* w3h = (h16*)alloc((size_t)E * F * H * sizeof(h16));
  h16* w2h = (h16*)alloc((size_t)E * H * F * sizeof(h16));
  bool pre = (off <= ws_size);
  (void)in_sizes; (void)n_in;

  k_init_counts<<<1, 64, 0, stream>>>(counts);
  k_zero_out<<<out_size / (256 * 4), 256, 0, stream>>>(out);
  k_routing<<<(T + 255) / 256, 256, 0, stream>>>(rl, topi, topw, counts);
  k_prefix<<<1, 64, 0, stream>>>(counts, offs, fill);
  k_scatter<<<(T + 255) / 256, 256, 0, stream>>>(topi, topw, offs, fill, etok, ew);
  k_cvt<<<(T * H / 8) / 256, 256, 0, stream>>>(x, x16);
  if (pre) {
    constexpr int WG = (E * F * H / 8) / 256;  // 11264
    k_cvt<<<WG, 256, 0, stream>>>(w1, w1h);
    k_cvt<<<WG, 256, 0, stream>>>(w3, w3h);
    k_cvt<<<WG, 256, 0, stream>>>(w2, w2h);
    k_gemm1<true><<<E * MT * NT1, 256, 0, stream>>>(x16, w1h, w3h, w1, w3, counts, offs, etok, act);
    k_gemm2<true><<<E * MT * NT2, 256, 0, stream>>>(act, w2h, w2, counts, offs, etok, ew, out);
  } else {
    k_gemm1<false><<<E * MT * NT1, 256, 0, stream>>>(x16, w1h, w3h, w1, w3, counts, offs, etok, act);
    k_gemm2<false><<<E * MT * NT2, 256, 0, stream>>>(act, w2h, w2, counts, offs, etok, ew, out);
  }
}

// Round 3
// 875.954 us; speedup vs baseline: 1.5526x; 1.0210x over previous
//
#include <hip/hip_runtime.h>
#include <hip/hip_bf16.h>

typedef _Float16 h16;
typedef _Float16 f16x8 __attribute__((ext_vector_type(8)));
typedef float f32x4 __attribute__((ext_vector_type(4)));

constexpr int T = 8192, H = 1024, F = 2816, E = 8;
constexpr int NENT = T * 2;
constexpr int SLACK = 128;
constexpr int MT = T / 128;     // 64 max M-tiles per expert
constexpr int NT1 = F / 128;    // 22
constexpr int NT2 = H / 128;    // 8

#define GLD16(gptr, lptr)                                                        \
  __builtin_amdgcn_global_load_lds(                                              \
      (const __attribute__((address_space(1))) unsigned int*)(gptr),             \
      (__attribute__((address_space(3))) unsigned int*)(lptr), 16, 0, 0)

// Swizzled LDS tile: 128 rows x 32 h16 (8 KB per buffer).
__device__ __forceinline__ int lds_off(int row, int s) {
  int r2 = row >> 1;
  int p = (((row & 1) << 2) | s) ^ (r2 & 7);
  return r2 * 128 + p * 16;
}
__device__ __forceinline__ void inv_rowcol(int c, int i, int& row, int& col) {
  int r2 = c * 8 + (i >> 3);
  int slot8 = (i & 7) ^ (r2 & 7);
  row = r2 * 2 + (slot8 >> 2);
  col = (slot8 & 3) * 8;
}

// ---------------- routing ----------------
__global__ void k_routing(const float* __restrict__ logits,
                          int* __restrict__ top_i, float* __restrict__ top_w,
                          int* __restrict__ counts) {
  int t = blockIdx.x * blockDim.x + threadIdx.x;
  if (t >= T) return;
  float l[E];
#pragma unroll
  for (int j = 0; j < E; ++j) l[j] = logits[t * E + j];
  int i1 = 0; float v1 = l[0];
#pragma unroll
  for (int j = 1; j < E; ++j) if (l[j] > v1) { v1 = l[j]; i1 = j; }
  int i2 = -1; float v2 = -3.4e38f;
#pragma unroll
  for (int j = 0; j < E; ++j) if (j != i1 && l[j] > v2) { v2 = l[j]; i2 = j; }
  float e2 = __expf(v2 - v1);
  float inv = 1.0f / (1.0f + e2);
  top_i[2 * t] = i1; top_i[2 * t + 1] = i2;
  top_w[2 * t] = inv; top_w[2 * t + 1] = e2 * inv;
  atomicAdd(&counts[i1], 1);
  atomicAdd(&counts[i2], 1);
}

__global__ void k_init_counts(int* counts) {
  if (threadIdx.x < E) counts[threadIdx.x] = 0;
}

__global__ void k_prefix(const int* __restrict__ counts, int* __restrict__ offs,
                         int* __restrict__ fill) {
  if (threadIdx.x == 0) {
    int s = 0;
    for (int e = 0; e < E; ++e) { offs[e] = s; s += counts[e]; fill[e] = 0; }
  }
}

__global__ void k_scatter(const int* __restrict__ top_i, const float* __restrict__ top_w,
                          const int* __restrict__ offs, int* __restrict__ fill,
                          int* __restrict__ etok, float* __restrict__ ew,
                          int* __restrict__ tok2ent) {
  int t = blockIdx.x * blockDim.x + threadIdx.x;
  if (t >= T) return;
#pragma unroll
  for (int k = 0; k < 2; ++k) {
    int e = top_i[2 * t + k];
    int pos = atomicAdd(&fill[e], 1);
    int idx = offs[e] + pos;
    etok[idx] = t;
    ew[idx] = top_w[2 * t + k];
    tok2ent[2 * t + k] = idx;
  }
}

// ---------------- fp32 -> fp16 ----------------
__global__ void k_cvt(const float* __restrict__ s, h16* __restrict__ d) {
  size_t i = (size_t)(blockIdx.x * blockDim.x + threadIdx.x) * 8;
  float4 a = *(const float4*)(s + i);
  float4 b = *(const float4*)(s + i + 4);
  f16x8 h = {(h16)a.x, (h16)a.y, (h16)a.z, (h16)a.w,
             (h16)b.x, (h16)b.y, (h16)b.z, (h16)b.w};
  *(f16x8*)(d + i) = h;
}

__global__ void k_zero_out(float* __restrict__ p) {
  int i = blockIdx.x * blockDim.x + threadIdx.x;
  ((float4*)p)[i] = make_float4(0.f, 0.f, 0.f, 0.f);
}

// ---------------- combine: out[t] = w0*y[p0] + w1*y[p1] ----------------
__global__ void k_combine(const h16* __restrict__ y, const int* __restrict__ tok2ent,
                          const float* __restrict__ topw, float* __restrict__ out) {
  int i = blockIdx.x * blockDim.x + threadIdx.x;   // one thread = 8 floats
  int t = i >> 7;            // H/8 = 128 threads per token
  int h0 = (i & 127) << 3;
  int p0 = tok2ent[2 * t], p1 = tok2ent[2 * t + 1];
  float w0 = topw[2 * t], w1 = topw[2 * t + 1];
  f16x8 y0 = *(const f16x8*)(y + (size_t)p0 * H + h0);
  f16x8 y1 = *(const f16x8*)(y + (size_t)p1 * H + h0);
  float4 o0, o1;
  o0.x = w0 * (float)y0[0] + w1 * (float)y1[0];
  o0.y = w0 * (float)y0[1] + w1 * (float)y1[1];
  o0.z = w0 * (float)y0[2] + w1 * (float)y1[2];
  o0.w = w0 * (float)y0[3] + w1 * (float)y1[3];
  o1.x = w0 * (float)y0[4] + w1 * (float)y1[4];
  o1.y = w0 * (float)y0[5] + w1 * (float)y1[5];
  o1.z = w0 * (float)y0[6] + w1 * (float)y1[6];
  o1.w = w0 * (float)y0[7] + w1 * (float)y1[7];
  *(float4*)(out + (size_t)t * H + h0) = o0;
  *(float4*)(out + (size_t)t * H + h0 + 4) = o1;
}

// ---------------- GEMM1: act = silu(Xg @ w1^T) * (Xg @ w3^T), 2-phase dbuf ----------------
template <bool BPRE>
__launch_bounds__(256, 2)
__global__ void k_gemm1(const h16* __restrict__ x16,
                        const h16* __restrict__ w1h, const h16* __restrict__ w3h,
                        const float* __restrict__ w1f, const float* __restrict__ w3f,
                        const int* __restrict__ counts, const int* __restrict__ offs,
                        const int* __restrict__ etok, h16* __restrict__ act) {
  int bid = blockIdx.x;
  int e  = bid / (MT * NT1);
  int r  = bid % (MT * NT1);
  int nt = r / MT;
  int mt = r % MT;
  int n_e = counts[e];
  if (mt * 128 >= n_e) return;
  int base = offs[e];

  __shared__ h16 As[2][128 * 32];
  __shared__ h16 B1s[2][128 * 32];
  __shared__ h16 B3s[2][128 * 32];

  int tid = threadIdx.x;
  int lane = tid & 63, wid = tid >> 6;
  int wm = (wid >> 1) * 64, wn = (wid & 1) * 64;
  int lr = lane & 15;
  int ls = lane >> 4;

  const h16* ga[2]; const h16* gb1[2]; const h16* gb3[2];
#pragma unroll
  for (int j = 0; j < 2; ++j) {
    int c = wid * 2 + j;
    int row, col;
    inv_rowcol(c, lane, row, col);
    int gr = mt * 128 + row; if (gr >= n_e) gr = n_e - 1;
    ga[j] = x16 + (size_t)etok[base + gr] * H + col;
    if (BPRE) {
      size_t wrow = ((size_t)e * F + (size_t)nt * 128 + row) * H + col;
      gb1[j] = w1h + wrow;
      gb3[j] = w3h + wrow;
    }
  }

  auto stage = [&](int b, int k0) {
#pragma unroll
    for (int j = 0; j < 2; ++j) {
      int c = wid * 2 + j;
      GLD16(ga[j] + k0, (char*)&As[b][0] + c * 1024);
      if (BPRE) {
        GLD16(gb1[j] + k0, (char*)&B1s[b][0] + c * 1024);
        GLD16(gb3[j] + k0, (char*)&B3s[b][0] + c * 1024);
      }
    }
    if (!BPRE) {
#pragma unroll
      for (int j = 0; j < 2; ++j) {
        int idx = tid * 2 + j;
        int r2 = idx >> 3, pp = idx & 7;
        int slot8 = pp ^ (r2 & 7);
        int row = r2 * 2 + (slot8 >> 2);
        int col = (slot8 & 3) * 8;
        size_t wrow = ((size_t)e * F + (size_t)nt * 128 + row) * H + col + k0;
        int ldso = r2 * 128 + pp * 16;
        float4 f0 = *(const float4*)(w1f + wrow);
        float4 f1 = *(const float4*)(w1f + wrow + 4);
        f16x8 h0 = {(h16)f0.x,(h16)f0.y,(h16)f0.z,(h16)f0.w,(h16)f1.x,(h16)f1.y,(h16)f1.z,(h16)f1.w};
        *(f16x8*)((char*)&B1s[b][0] + ldso) = h0;
        float4 g0 = *(const float4*)(w3f + wrow);
        float4 g1 = *(const float4*)(w3f + wrow + 4);
        f16x8 h1 = {(h16)g0.x,(h16)g0.y,(h16)g0.z,(h16)g0.w,(h16)g1.x,(h16)g1.y,(h16)g1.z,(h16)g1.w};
        *(f16x8*)((char*)&B3s[b][0] + ldso) = h1;
      }
    }
  };

  f32x4 accg[4][4] = {{{0.f,0.f,0.f,0.f}}};
  f32x4 accu[4][4] = {{{0.f,0.f,0.f,0.f}}};

  int aoff[4], boff[4];
#pragma unroll
  for (int i = 0; i < 4; ++i) {
    aoff[i] = lds_off(wm + i * 16 + lr, ls);
    boff[i] = lds_off(wn + i * 16 + lr, ls);
  }

  stage(0, 0);
  __syncthreads();
  int cur = 0;
  for (int k0 = 0; k0 < H; k0 += 32) {
    if (k0 + 32 < H) stage(cur ^ 1, k0 + 32);
    const char* ab  = (const char*)&As[cur][0];
    const char* b1b = (const char*)&B1s[cur][0];
    const char* b3b = (const char*)&B3s[cur][0];
    f16x8 av[4], b1v[4], b3v[4];
#pragma unroll
    for (int mi = 0; mi < 4; ++mi) av[mi] = *(const f16x8*)(ab + aoff[mi]);
#pragma unroll
    for (int ni = 0; ni < 4; ++ni) {
      b1v[ni] = *(const f16x8*)(b1b + boff[ni]);
      b3v[ni] = *(const f16x8*)(b3b + boff[ni]);
    }
#pragma unroll
    for (int mi = 0; mi < 4; ++mi)
#pragma unroll
      for (int ni = 0; ni < 4; ++ni) {
        accg[mi][ni] = __builtin_amdgcn_mfma_f32_16x16x32_f16(av[mi], b1v[ni], accg[mi][ni], 0, 0, 0);
        accu[mi][ni] = __builtin_amdgcn_mfma_f32_16x16x32_f16(av[mi], b3v[ni], accu[mi][ni], 0, 0, 0);
      }
    __syncthreads();
    cur ^= 1;
  }

#pragma unroll
  for (int mi = 0; mi < 4; ++mi) {
#pragma unroll
    for (int rr = 0; rr < 4; ++rr) {
      int grow = mt * 128 + wm + mi * 16 + (lane >> 4) * 4 + rr;
      if (grow < n_e) {
        size_t rowb = (size_t)(base + grow) * F + (size_t)nt * 128 + wn;
#pragma unroll
        for (int ni = 0; ni < 4; ++ni) {
          float g = accg[mi][ni][rr];
          float u = accu[mi][ni][rr];
          float s = g / (1.0f + __expf(-g)) * u;
          act[rowb + ni * 16 + lr] = (h16)s;
        }
      }
    }
  }
}

// ---------------- GEMM2: y[entry] = act @ w2^T (fp16), or atomic fallback ----------------
template <bool BPRE, bool YB>
__launch_bounds__(256, 3)
__global__ void k_gemm2(const h16* __restrict__ act,
                        const h16* __restrict__ w2h, const float* __restrict__ w2f,
                        const int* __restrict__ counts, const int* __restrict__ offs,
                        const int* __restrict__ etok, const float* __restrict__ ew,
                        h16* __restrict__ y16, float* __restrict__ out) {
  int bid = blockIdx.x;
  int e  = bid / (MT * NT2);
  int r  = bid % (MT * NT2);
  int nt = r / MT;
  int mt = r % MT;
  int n_e = counts[e];
  if (mt * 128 >= n_e) return;
  int base = offs[e];

  __shared__ h16 As[2][128 * 32];
  __shared__ h16 Bs[2][128 * 32];

  int tid = threadIdx.x;
  int lane = tid & 63, wid = tid >> 6;
  int wm = (wid >> 1) * 64, wn = (wid & 1) * 64;
  int lr = lane & 15;
  int ls = lane >> 4;

  const h16* ga[2]; const h16* gb[2];
#pragma unroll
  for (int j = 0; j < 2; ++j) {
    int c = wid * 2 + j;
    int row, col;
    inv_rowcol(c, lane, row, col);
    int gr = mt * 128 + row; if (gr >= n_e) gr = n_e - 1;
    ga[j] = act + (size_t)(base + gr) * F + col;
    if (BPRE) gb[j] = w2h + ((size_t)e * H + (size_t)nt * 128 + row) * F + col;
  }

  auto stage = [&](int b, int k0) {
#pragma unroll
    for (int j = 0; j < 2; ++j) {
      int c = wid * 2 + j;
      GLD16(ga[j] + k0, (char*)&As[b][0] + c * 1024);
      if (BPRE) GLD16(gb[j] + k0, (char*)&Bs[b][0] + c * 1024);
    }
    if (!BPRE) {
#pragma unroll
      for (int j = 0; j < 2; ++j) {
        int idx = tid * 2 + j;
        int r2 = idx >> 3, pp = idx & 7;
        int slot8 = pp ^ (r2 & 7);
        int row = r2 * 2 + (slot8 >> 2);
        int col = (slot8 & 3) * 8;
        size_t wrow = ((size_t)e * H + (size_t)nt * 128 + row) * F + col + k0;
        int ldso = r2 * 128 + pp * 16;
        float4 f0 = *(const float4*)(w2f + wrow);
        float4 f1 = *(const float4*)(w2f + wrow + 4);
        f16x8 h0 = {(h16)f0.x,(h16)f0.y,(h16)f0.z,(h16)f0.w,(h16)f1.x,(h16)f1.y,(h16)f1.z,(h16)f1.w};
        *(f16x8*)((char*)&Bs[b][0] + ldso) = h0;
      }
    }
  };

  f32x4 acc[4][4] = {{{0.f,0.f,0.f,0.f}}};

  int aoff[4], boff[4];
#pragma unroll
  for (int i = 0; i < 4; ++i) {
    aoff[i] = lds_off(wm + i * 16 + lr, ls);
    boff[i] = lds_off(wn + i * 16 + lr, ls);
  }

  stage(0, 0);
  __syncthreads();
  int cur = 0;
  for (int k0 = 0; k0 < F; k0 += 32) {
    if (k0 + 32 < F) stage(cur ^ 1, k0 + 32);
    const char* ab = (const char*)&As[cur][0];
    const char* bb = (const char*)&Bs[cur][0];
    f16x8 av[4], bv[4];
#pragma unroll
    for (int mi = 0; mi < 4; ++mi) av[mi] = *(const f16x8*)(ab + aoff[mi]);
#pragma unroll
    for (int ni = 0; ni < 4; ++ni) bv[ni] = *(const f16x8*)(bb + boff[ni]);
#pragma unroll
    for (int mi = 0; mi < 4; ++mi)
#pragma unroll
      for (int ni = 0; ni < 4; ++ni)
        acc[mi][ni] = __builtin_amdgcn_mfma_f32_16x16x32_f16(av[mi], bv[ni], acc[mi][ni], 0, 0, 0);
    __syncthreads();
    cur ^= 1;
  }

#pragma unroll
  for (int mi = 0; mi < 4; ++mi) {
#pragma unroll
    for (int rr = 0; rr < 4; ++rr) {
      int grow = mt * 128 + wm + mi * 16 + (lane >> 4) * 4 + rr;
      if (grow < n_e) {
        if (YB) {
          h16* yrow = y16 + (size_t)(base + grow) * H + (size_t)nt * 128 + wn;
#pragma unroll
          for (int ni = 0; ni < 4; ++ni)
            yrow[ni * 16 + lr] = (h16)acc[mi][ni][rr];
        } else {
          int tok = etok[base + grow];
          float w = ew[base + grow];
          float* orow = out + (size_t)tok * H + (size_t)nt * 128 + wn;
#pragma unroll
          for (int ni = 0; ni < 4; ++ni)
            atomicAdd(orow + ni * 16 + lr, w * acc[mi][ni][rr]);
        }
      }
    }
  }
}

extern "C" void kernel_launch(void* const* d_in, const int* in_sizes, int n_in,
                              void* d_out, int out_size, void* d_ws, size_t ws_size,
                              hipStream_t stream) {
  const float* x  = (const float*)d_in[0];
  const float* rl = (const float*)d_in[1];
  const float* w1 = (const float*)d_in[2];
  const float* w3 = (const float*)d_in[3];
  const float* w2 = (const float*)d_in[4];
  float* out = (float*)d_out;

  char* ws = (char*)d_ws;
  size_t off = 0;
  auto alloc = [&](size_t bytes) -> void* {
    void* p = ws + off;
    off = (off + bytes + 255) & ~(size_t)255;
    return p;
  };
  h16*   x16  = (h16*)  alloc((size_t)T * H * sizeof(h16));
  h16*   act  = (h16*)  alloc((size_t)(NENT + SLACK) * F * sizeof(h16));
  int*   etok = (int*)  alloc((size_t)(NENT + SLACK) * sizeof(int));
  float* ew   = (float*)alloc((size_t)(NENT + SLACK) * sizeof(float));
  int*   topi = (int*)  alloc((size_t)NENT * sizeof(int));
  float* topw = (float*)alloc((size_t)NENT * sizeof(float));
  int* tok2ent = (int*) alloc((size_t)NENT * sizeof(int));
  int* counts = (int*)  alloc(64);
  int* offs   = (int*)  alloc(64);
  int* fill   = (int*)  alloc(64);
  h16* w1h = (h16*)alloc((size_t)E * F * H * sizeof(h16));
  h16* w3h = (h16*)alloc((size_t)E * F * H * sizeof(h16));
  h16* w2h = (h16*)alloc((size_t)E * H * F * sizeof(h16));
  bool pre = (off <= ws_size);
  h16* y16 = (h16*)alloc((size_t)(NENT + SLACK) * H * sizeof(h16));
  bool yb = (off <= ws_size);
  (void)in_sizes; (void)n_in;

  k_init_counts<<<1, 64, 0, stream>>>(counts);
  if (!yb) k_zero_out<<<out_size / (256 * 4), 256, 0, stream>>>(out);
  k_routing<<<(T + 255) / 256, 256, 0, stream>>>(rl, topi, topw, counts);
  k_prefix<<<1, 64, 0, stream>>>(counts, offs, fill);
  k_scatter<<<(T + 255) / 256, 256, 0, stream>>>(topi, topw, offs, fill, etok, ew, tok2ent);
  k_cvt<<<(T * H / 8) / 256, 256, 0, stream>>>(x, x16);
  if (pre) {
    constexpr int WG = (E * F * H / 8) / 256;  // 11264
    k_cvt<<<WG, 256, 0, stream>>>(w1, w1h);
    k_cvt<<<WG, 256, 0, stream>>>(w3, w3h);
    k_cvt<<<WG, 256, 0, stream>>>(w2, w2h);
    k_gemm1<true><<<E * MT * NT1, 256, 0, stream>>>(x16, w1h, w3h, w1, w3, counts, offs, etok, act);
    if (yb) k_gemm2<true, true ><<<E * MT * NT2, 256, 0, stream>>>(act, w2h, w2, counts, offs, etok, ew, y16, out);
    else    k_gemm2<true, false><<<E * MT * NT2, 256, 0, stream>>>(act, w2h, w2, counts, offs, etok, ew, y16, out);
  } else {
    k_gemm1<false><<<E * MT * NT1, 256, 0, stream>>>(x16, w1h, w3h, w1, w3, counts, offs, etok, act);
    k_gemm2<false, false><<<E * MT * NT2, 256, 0, stream>>>(act, w2h, w2, counts, offs, etok, ew, y16, out);
  }
  if (yb) k_combine<<<(T * H / 8) / 256, 256, 0, stream>>>(y16, tok2ent, topw, out);
}

// Round 4
// 666.483 us; speedup vs baseline: 2.0406x; 1.3143x over previous
//
#include <hip/hip_runtime.h>
#include <hip/hip_bf16.h>

typedef _Float16 h16;
typedef _Float16 f16x8 __attribute__((ext_vector_type(8)));
typedef float f32x4 __attribute__((ext_vector_type(4)));

constexpr int T = 8192, H = 1024, F = 2816, E = 8;
constexpr int NENT = T * 2;
constexpr int SLACK = 128;
constexpr int BM = 256, BK = 64;
constexpr int MT256 = T / BM;       // 32
constexpr int NT1b = F / 128;       // 22  (gemm1 BN=128)
constexpr int NT2b = H / 256;       // 4   (gemm2 BN=256)
constexpr int NKH = H / BK;         // 16
constexpr int NKF = F / BK;         // 44

#define GLD16(gptr, lptr)                                                        \
  __builtin_amdgcn_global_load_lds(                                              \
      (const __attribute__((address_space(1))) unsigned int*)(gptr),             \
      (__attribute__((address_space(3))) unsigned int*)(lptr), 16, 0, 0)

#define ASM_VMCNT(n) asm volatile("s_waitcnt vmcnt(" #n ")" ::: "memory")
#define ASM_LGKM0    asm volatile("s_waitcnt lgkmcnt(0)" ::: "memory")
#define SBAR()       __builtin_amdgcn_s_barrier()
#define SCHEDB()     __builtin_amdgcn_sched_barrier(0)

// LDS tile: rows x 64 h16 (128 B/row). k-slot s in [0,8) of 8 h16; phys slot
// = s ^ (row&7). global_load_lds chunk c (1 KB), lane i writes linear byte
// c*1024 + i*16 -> row = c*8 + (i>>3), phys slot i&7 -> logical
// s = (i&7) ^ ((i>>3)&7)  (c*8 doesn't affect row&7).
__device__ __forceinline__ int src_col(int lane) {
  return (((lane & 7) ^ ((lane >> 3) & 7)) * 8);
}
__device__ __forceinline__ int frag_off(int row, int s) {
  return row * 128 + ((s ^ (row & 7)) * 16);
}

// ---------------- routing ----------------
__global__ void k_routing(const float* __restrict__ logits,
                          int* __restrict__ top_i, float* __restrict__ top_w,
                          int* __restrict__ counts) {
  int t = blockIdx.x * blockDim.x + threadIdx.x;
  if (t >= T) return;
  float l[E];
#pragma unroll
  for (int j = 0; j < E; ++j) l[j] = logits[t * E + j];
  int i1 = 0; float v1 = l[0];
#pragma unroll
  for (int j = 1; j < E; ++j) if (l[j] > v1) { v1 = l[j]; i1 = j; }
  int i2 = -1; float v2 = -3.4e38f;
#pragma unroll
  for (int j = 0; j < E; ++j) if (j != i1 && l[j] > v2) { v2 = l[j]; i2 = j; }
  float e2 = __expf(v2 - v1);
  float inv = 1.0f / (1.0f + e2);
  top_i[2 * t] = i1; top_i[2 * t + 1] = i2;
  top_w[2 * t] = inv; top_w[2 * t + 1] = e2 * inv;
  atomicAdd(&counts[i1], 1);
  atomicAdd(&counts[i2], 1);
}

__global__ void k_init_counts(int* counts) {
  if (threadIdx.x < E) counts[threadIdx.x] = 0;
}

__global__ void k_prefix(const int* __restrict__ counts, int* __restrict__ offs,
                         int* __restrict__ fill) {
  if (threadIdx.x == 0) {
    int s = 0;
    for (int e = 0; e < E; ++e) { offs[e] = s; s += counts[e]; fill[e] = 0; }
  }
}

__global__ void k_scatter(const int* __restrict__ top_i, const float* __restrict__ top_w,
                          const int* __restrict__ offs, int* __restrict__ fill,
                          int* __restrict__ etok, float* __restrict__ ew,
                          int* __restrict__ tok2ent) {
  int t = blockIdx.x * blockDim.x + threadIdx.x;
  if (t >= T) return;
#pragma unroll
  for (int k = 0; k < 2; ++k) {
    int e = top_i[2 * t + k];
    int pos = atomicAdd(&fill[e], 1);
    int idx = offs[e] + pos;
    etok[idx] = t;
    ew[idx] = top_w[2 * t + k];
    tok2ent[2 * t + k] = idx;
  }
}

// ---------------- fp32 -> fp16 ----------------
__global__ void k_cvt(const float* __restrict__ s, h16* __restrict__ d) {
  size_t i = (size_t)(blockIdx.x * blockDim.x + threadIdx.x) * 8;
  float4 a = *(const float4*)(s + i);
  float4 b = *(const float4*)(s + i + 4);
  f16x8 h = {(h16)a.x, (h16)a.y, (h16)a.z, (h16)a.w,
             (h16)b.x, (h16)b.y, (h16)b.z, (h16)b.w};
  *(f16x8*)(d + i) = h;
}

// ---------------- combine: out[t] = w0*y[p0] + w1*y[p1] ----------------
__global__ void k_combine(const h16* __restrict__ y, const int* __restrict__ tok2ent,
                          const float* __restrict__ topw, float* __restrict__ out) {
  int i = blockIdx.x * blockDim.x + threadIdx.x;
  int t = i >> 7;
  int h0 = (i & 127) << 3;
  int p0 = tok2ent[2 * t], p1 = tok2ent[2 * t + 1];
  float w0 = topw[2 * t], w1 = topw[2 * t + 1];
  f16x8 y0 = *(const f16x8*)(y + (size_t)p0 * H + h0);
  f16x8 y1 = *(const f16x8*)(y + (size_t)p1 * H + h0);
  float4 o0, o1;
  o0.x = w0 * (float)y0[0] + w1 * (float)y1[0];
  o0.y = w0 * (float)y0[1] + w1 * (float)y1[1];
  o0.z = w0 * (float)y0[2] + w1 * (float)y1[2];
  o0.w = w0 * (float)y0[3] + w1 * (float)y1[3];
  o1.x = w0 * (float)y0[4] + w1 * (float)y1[4];
  o1.y = w0 * (float)y0[5] + w1 * (float)y1[5];
  o1.z = w0 * (float)y0[6] + w1 * (float)y1[6];
  o1.w = w0 * (float)y0[7] + w1 * (float)y1[7];
  *(float4*)(out + (size_t)t * H + h0) = o0;
  *(float4*)(out + (size_t)t * H + h0 + 4) = o1;
}

// ---------------- GEMM1: 256x128 tile, gate+up fused, 2-deep counted-vmcnt ----------------
__launch_bounds__(512, 2)
__global__ void k_gemm1(const h16* __restrict__ x16,
                        const h16* __restrict__ w1h, const h16* __restrict__ w3h,
                        const int* __restrict__ counts, const int* __restrict__ offs,
                        const int* __restrict__ etok, h16* __restrict__ act) {
  constexpr int NWG = E * MT256 * NT1b;              // 5632, %8==0
  int orig = blockIdx.x;
  int bid = (orig & 7) * (NWG / 8) + (orig >> 3);    // XCD-chunked swizzle
  int e  = bid / (MT256 * NT1b);
  int r  = bid % (MT256 * NT1b);
  int nt = r / MT256;
  int mt = r % MT256;
  int n_e = counts[e];
  if (mt * BM >= n_e) return;
  int base = offs[e];

  __shared__ h16 As[2][BM * BK];      // 32 KB each
  __shared__ h16 B1s[2][128 * BK];    // 16 KB each
  __shared__ h16 B3s[2][128 * BK];    // 16 KB each

  int tid = threadIdx.x;
  int lane = tid & 63, wid = tid >> 6;
  int wm = (wid >> 2) * 128;          // 2 M-groups
  int wn = (wid & 3) * 32;            // 4 N-groups
  int lr = lane & 15, ls = lane >> 4;

  // staging sources
  const h16* gA[4];
#pragma unroll
  for (int j = 0; j < 4; ++j) {
    int c = wid * 4 + j;
    int row = c * 8 + (lane >> 3);
    int gr = mt * BM + row; if (gr >= n_e) gr = n_e - 1;
    gA[j] = x16 + (size_t)etok[base + gr] * H + src_col(lane);
  }
  const h16* gB1[2]; const h16* gB3[2];
#pragma unroll
  for (int j = 0; j < 2; ++j) {
    int c = wid * 2 + j;
    int row = c * 8 + (lane >> 3);
    size_t w = ((size_t)e * F + (size_t)nt * 128 + row) * H + src_col(lane);
    gB1[j] = w1h + w;
    gB3[j] = w3h + w;
  }

  auto stage = [&](int b, int k0) {
#pragma unroll
    for (int j = 0; j < 4; ++j)
      GLD16(gA[j] + k0, (char*)&As[b][0] + (wid * 4 + j) * 1024);
#pragma unroll
    for (int j = 0; j < 2; ++j) {
      GLD16(gB1[j] + k0, (char*)&B1s[b][0] + (wid * 2 + j) * 1024);
      GLD16(gB3[j] + k0, (char*)&B3s[b][0] + (wid * 2 + j) * 1024);
    }
  };

  // frag LDS byte offsets
  int aoff[8][2], boff[2][2];
#pragma unroll
  for (int mi = 0; mi < 8; ++mi)
#pragma unroll
    for (int h = 0; h < 2; ++h)
      aoff[mi][h] = frag_off(wm + mi * 16 + lr, h * 4 + ls);
#pragma unroll
  for (int nj = 0; nj < 2; ++nj)
#pragma unroll
    for (int h = 0; h < 2; ++h)
      boff[nj][h] = frag_off(wn + nj * 16 + lr, h * 4 + ls);

  f32x4 ag[8][2] = {{{0.f,0.f,0.f,0.f}}};
  f32x4 au[8][2] = {{{0.f,0.f,0.f,0.f}}};

  stage(0, 0);
  stage(1, BK);
  int cur = 0;
  for (int t = 0; t < NKH; ++t) {
    if (t + 1 < NKH) { ASM_VMCNT(8); } else { ASM_VMCNT(0); }
    SBAR();                                  // buf[cur] ready for all waves
    const char* ab  = (const char*)&As[cur][0];
    const char* b1b = (const char*)&B1s[cur][0];
    const char* b3b = (const char*)&B3s[cur][0];
    // ---- k-half 0 ----
    f16x8 av0[8], b1v0[2], b3v0[2];
#pragma unroll
    for (int mi = 0; mi < 8; ++mi) av0[mi] = *(const f16x8*)(ab + aoff[mi][0]);
#pragma unroll
    for (int nj = 0; nj < 2; ++nj) {
      b1v0[nj] = *(const f16x8*)(b1b + boff[nj][0]);
      b3v0[nj] = *(const f16x8*)(b3b + boff[nj][0]);
    }
    __builtin_amdgcn_s_setprio(1);
#pragma unroll
    for (int mi = 0; mi < 8; ++mi)
#pragma unroll
      for (int nj = 0; nj < 2; ++nj) {
        ag[mi][nj] = __builtin_amdgcn_mfma_f32_16x16x32_f16(av0[mi], b1v0[nj], ag[mi][nj], 0, 0, 0);
        au[mi][nj] = __builtin_amdgcn_mfma_f32_16x16x32_f16(av0[mi], b3v0[nj], au[mi][nj], 0, 0, 0);
      }
    __builtin_amdgcn_s_setprio(0);
    // ---- k-half 1 ----
    f16x8 av1[8], b1v1[2], b3v1[2];
#pragma unroll
    for (int mi = 0; mi < 8; ++mi) av1[mi] = *(const f16x8*)(ab + aoff[mi][1]);
#pragma unroll
    for (int nj = 0; nj < 2; ++nj) {
      b1v1[nj] = *(const f16x8*)(b1b + boff[nj][1]);
      b3v1[nj] = *(const f16x8*)(b3b + boff[nj][1]);
    }
    ASM_LGKM0;                               // all my ds_reads of buf[cur] done
    SCHEDB();
    SBAR();                                  // ... for every wave
    if (t + 2 < NKH) stage(cur, (t + 2) * BK);   // overwrite buf[cur] safely
    __builtin_amdgcn_s_setprio(1);
#pragma unroll
    for (int mi = 0; mi < 8; ++mi)
#pragma unroll
      for (int nj = 0; nj < 2; ++nj) {
        ag[mi][nj] = __builtin_amdgcn_mfma_f32_16x16x32_f16(av1[mi], b1v1[nj], ag[mi][nj], 0, 0, 0);
        au[mi][nj] = __builtin_amdgcn_mfma_f32_16x16x32_f16(av1[mi], b3v1[nj], au[mi][nj], 0, 0, 0);
      }
    __builtin_amdgcn_s_setprio(0);
    cur ^= 1;
  }

  // epilogue: silu(g)*u -> act fp16
#pragma unroll
  for (int mi = 0; mi < 8; ++mi) {
#pragma unroll
    for (int rr = 0; rr < 4; ++rr) {
      int grow = mt * BM + wm + mi * 16 + ls * 4 + rr;
      if (grow < n_e) {
        size_t rowb = (size_t)(base + grow) * F + (size_t)nt * 128 + wn;
#pragma unroll
        for (int nj = 0; nj < 2; ++nj) {
          float g = ag[mi][nj][rr];
          float u = au[mi][nj][rr];
          float s = g / (1.0f + __expf(-g)) * u;
          act[rowb + nj * 16 + lr] = (h16)s;
        }
      }
    }
  }
}

// ---------------- GEMM2: 256x256 tile, y = act @ w2^T ----------------
__launch_bounds__(512, 2)
__global__ void k_gemm2(const h16* __restrict__ act, const h16* __restrict__ w2h,
                        const int* __restrict__ counts, const int* __restrict__ offs,
                        h16* __restrict__ y16) {
  constexpr int NWG = E * MT256 * NT2b;              // 1024, %8==0
  int orig = blockIdx.x;
  int bid = (orig & 7) * (NWG / 8) + (orig >> 3);
  int e  = bid / (MT256 * NT2b);
  int r  = bid % (MT256 * NT2b);
  int nt = r / MT256;
  int mt = r % MT256;
  int n_e = counts[e];
  if (mt * BM >= n_e) return;
  int base = offs[e];

  __shared__ h16 As[2][BM * BK];      // 32 KB each
  __shared__ h16 Bs[2][BM * BK];      // 32 KB each (256 rows)

  int tid = threadIdx.x;
  int lane = tid & 63, wid = tid >> 6;
  int wm = (wid >> 2) * 128;
  int wn = (wid & 3) * 64;
  int lr = lane & 15, ls = lane >> 4;

  const h16* gA[4]; const h16* gB[4];
#pragma unroll
  for (int j = 0; j < 4; ++j) {
    int c = wid * 4 + j;
    int row = c * 8 + (lane >> 3);
    int gr = mt * BM + row; if (gr >= n_e) gr = n_e - 1;
    gA[j] = act + (size_t)(base + gr) * F + src_col(lane);
    gB[j] = w2h + ((size_t)e * H + (size_t)nt * 256 + row) * F + src_col(lane);
  }

  auto stage = [&](int b, int k0) {
#pragma unroll
    for (int j = 0; j < 4; ++j) {
      GLD16(gA[j] + k0, (char*)&As[b][0] + (wid * 4 + j) * 1024);
      GLD16(gB[j] + k0, (char*)&Bs[b][0] + (wid * 4 + j) * 1024);
    }
  };

  int aoff[8][2], boff[4][2];
#pragma unroll
  for (int mi = 0; mi < 8; ++mi)
#pragma unroll
    for (int h = 0; h < 2; ++h)
      aoff[mi][h] = frag_off(wm + mi * 16 + lr, h * 4 + ls);
#pragma unroll
  for (int nj = 0; nj < 4; ++nj)
#pragma unroll
    for (int h = 0; h < 2; ++h)
      boff[nj][h] = frag_off(wn + nj * 16 + lr, h * 4 + ls);

  f32x4 acc[8][4] = {{{0.f,0.f,0.f,0.f}}};

  stage(0, 0);
  stage(1, BK);
  int cur = 0;
  for (int t = 0; t < NKF; ++t) {
    if (t + 1 < NKF) { ASM_VMCNT(8); } else { ASM_VMCNT(0); }
    SBAR();
    const char* ab = (const char*)&As[cur][0];
    const char* bb = (const char*)&Bs[cur][0];
    f16x8 av0[8], bv0[4];
#pragma unroll
    for (int mi = 0; mi < 8; ++mi) av0[mi] = *(const f16x8*)(ab + aoff[mi][0]);
#pragma unroll
    for (int nj = 0; nj < 4; ++nj) bv0[nj] = *(const f16x8*)(bb + boff[nj][0]);
    __builtin_amdgcn_s_setprio(1);
#pragma unroll
    for (int mi = 0; mi < 8; ++mi)
#pragma unroll
      for (int nj = 0; nj < 4; ++nj)
        acc[mi][nj] = __builtin_amdgcn_mfma_f32_16x16x32_f16(av0[mi], bv0[nj], acc[mi][nj], 0, 0, 0);
    __builtin_amdgcn_s_setprio(0);
    f16x8 av1[8], bv1[4];
#pragma unroll
    for (int mi = 0; mi < 8; ++mi) av1[mi] = *(const f16x8*)(ab + aoff[mi][1]);
#pragma unroll
    for (int nj = 0; nj < 4; ++nj) bv1[nj] = *(const f16x8*)(bb + boff[nj][1]);
    ASM_LGKM0;
    SCHEDB();
    SBAR();
    if (t + 2 < NKF) stage(cur, (t + 2) * BK);
    __builtin_amdgcn_s_setprio(1);
#pragma unroll
    for (int mi = 0; mi < 8; ++mi)
#pragma unroll
      for (int nj = 0; nj < 4; ++nj)
        acc[mi][nj] = __builtin_amdgcn_mfma_f32_16x16x32_f16(av1[mi], bv1[nj], acc[mi][nj], 0, 0, 0);
    __builtin_amdgcn_s_setprio(0);
    cur ^= 1;
  }

#pragma unroll
  for (int mi = 0; mi < 8; ++mi) {
#pragma unroll
    for (int rr = 0; rr < 4; ++rr) {
      int grow = mt * BM + wm + mi * 16 + ls * 4 + rr;
      if (grow < n_e) {
        h16* yrow = y16 + (size_t)(base + grow) * H + (size_t)nt * 256 + wn;
#pragma unroll
        for (int nj = 0; nj < 4; ++nj)
          yrow[nj * 16 + lr] = (h16)acc[mi][nj][rr];
      }
    }
  }
}

extern "C" void kernel_launch(void* const* d_in, const int* in_sizes, int n_in,
                              void* d_out, int out_size, void* d_ws, size_t ws_size,
                              hipStream_t stream) {
  const float* x  = (const float*)d_in[0];
  const float* rl = (const float*)d_in[1];
  const float* w1 = (const float*)d_in[2];
  const float* w3 = (const float*)d_in[3];
  const float* w2 = (const float*)d_in[4];
  float* out = (float*)d_out;

  char* ws = (char*)d_ws;
  size_t off = 0;
  auto alloc = [&](size_t bytes) -> void* {
    void* p = ws + off;
    off = (off + bytes + 255) & ~(size_t)255;
    return p;
  };
  h16*   x16  = (h16*)  alloc((size_t)T * H * sizeof(h16));
  h16*   act  = (h16*)  alloc((size_t)(NENT + SLACK) * F * sizeof(h16));
  int*   etok = (int*)  alloc((size_t)(NENT + SLACK) * sizeof(int));
  float* ew   = (float*)alloc((size_t)(NENT + SLACK) * sizeof(float));
  int*   topi = (int*)  alloc((size_t)NENT * sizeof(int));
  float* topw = (float*)alloc((size_t)NENT * sizeof(float));
  int* tok2ent = (int*) alloc((size_t)NENT * sizeof(int));
  int* counts = (int*)  alloc(64);
  int* offs   = (int*)  alloc(64);
  int* fill   = (int*)  alloc(64);
  h16* w1h = (h16*)alloc((size_t)E * F * H * sizeof(h16));
  h16* w3h = (h16*)alloc((size_t)E * F * H * sizeof(h16));
  h16* w2h = (h16*)alloc((size_t)E * H * F * sizeof(h16));
  h16* y16 = (h16*)alloc((size_t)(NENT + SLACK) * H * sizeof(h16));
  (void)in_sizes; (void)n_in; (void)ws_size;

  k_init_counts<<<1, 64, 0, stream>>>(counts);
  k_routing<<<(T + 255) / 256, 256, 0, stream>>>(rl, topi, topw, counts);
  k_prefix<<<1, 64, 0, stream>>>(counts, offs, fill);
  k_scatter<<<(T + 255) / 256, 256, 0, stream>>>(topi, topw, offs, fill, etok, ew, tok2ent);
  k_cvt<<<(T * H / 8) / 256, 256, 0, stream>>>(x, x16);
  constexpr int WG = (E * F * H / 8) / 256;  // 11264
  k_cvt<<<WG, 256, 0, stream>>>(w1, w1h);
  k_cvt<<<WG, 256, 0, stream>>>(w3, w3h);
  k_cvt<<<WG, 256, 0, stream>>>(w2, w2h);
  k_gemm1<<<E * MT256 * NT1b, 512, 0, stream>>>(x16, w1h, w3h, counts, offs, etok, act);
  k_gemm2<<<E * MT256 * NT2b, 512, 0, stream>>>(act, w2h, counts, offs, y16);
  k_combine<<<(T * H / 8) / 256, 256, 0, stream>>>(y16, tok2ent, topw, out);
}